// Round 2
// baseline (252.129 us; speedup 1.0000x reference)
//
#include <hip/hip_runtime.h>

// SRM block fused kernel, M=4, S=2, B=2, C=128, H=W=512.
//
// Index algebra (verified by round-1 pass): per window (P,Q) the 16 source
// coords of the rearrange equal the 16 destination coords of the restore,
// slot-for-slot: rows {4P-2,4P-1,4P+4,4P+5}, cols {4Q-2,4Q-1,4Q+4,4Q+5},
// clamped to {0,1}/{510,511} at the edges. Column pairs map bijectively:
// window Q reads/writes pairs {2Q-1, 2Q+2} (clamped) — so a lane-dense
// float4 at col 4Q+2 (= pairs {2Q+1,2Q+2}) gives lane Q its pair1 directly
// and lane Q+1 its pair0 via __shfl_up. Wave-edge lanes patch with float2.
//
// Each thread handles TWO windows (P = 2*P2, 2*P2+1; same Q) so each LDS
// weight read (ds_read_b128 broadcast) feeds two FMAs — halves the LDS
// broadcast pipe traffic that was co-saturating with HBM in round 1.

#define WDIM 512

typedef float f4 __attribute__((ext_vector_type(4)));
typedef float f2 __attribute__((ext_vector_type(2)));

__global__ __launch_bounds__(256) void srm_fused_kernel(
    const float* __restrict__ x, const float* __restrict__ fw,
    const float* __restrict__ fb, float* __restrict__ out)
{
    __shared__ __align__(16) float sw[16][16];
    __shared__ float sb[16];
    const int tid = threadIdx.x;
    sw[tid >> 4][tid & 15] = fw[tid];       // 256 weights
    if (tid < 16) sb[tid] = fb[tid];
    __syncthreads();

    const int wid  = blockIdx.x * 256 + tid;
    const int Q    = wid & 127;
    const int P2   = (wid >> 7) & 63;
    const int bc   = wid >> 13;             // b*C + c in [0,256)
    const int lane = tid & 63;
    const bool firstlane = (lane == 0);     // Q in {0, 64}
    const bool lastlane  = (lane == 63);    // Q in {63, 127}

    const int PA = 2 * P2, PB = 2 * P2 + 1;
    const int c0 = (Q == 0)   ? 0   : 4 * Q - 2;
    const int c2 = (Q == 127) ? 510 : 4 * Q + 4;

    int rows[8];
    {
        const int a0 = (PA == 0) ? 0 : 4 * PA - 2;   // PA <= 126 -> a2 never clamps
        const int a2 = 4 * PA + 4;
        const int b0 = 4 * PB - 2;                   // PB >= 1 -> b0 never clamps
        const int b2 = (PB == 127) ? 510 : 4 * PB + 4;
        rows[0] = a0; rows[1] = a0 + 1; rows[2] = a2; rows[3] = a2 + 1;
        rows[4] = b0; rows[5] = b0 + 1; rows[6] = b2; rows[7] = b2 + 1;
    }

    const float* xp = x   + (size_t)bc * (512 * 512);
    float*       op = out + (size_t)bc * (512 * 512);

    // ---- gather: dense float4 + shfl_up; wave-edge lane patches with float2
    float v[32];
#pragma unroll
    for (int r = 0; r < 8; ++r) {
        const float* rowp = xp + rows[r] * WDIM;
        f4 A = *reinterpret_cast<const f4*>(rowp + c2 - 2);  // pairs {2Q+1, 2Q+2}
        float p0x = __shfl_up(A.x, 1);
        float p0y = __shfl_up(A.y, 1);
        if (firstlane) {
            f2 e = *reinterpret_cast<const f2*>(rowp + c0);
            p0x = e.x; p0y = e.y;
        }
        v[r * 4 + 0] = p0x; v[r * 4 + 1] = p0y;
        v[r * 4 + 2] = A.z; v[r * 4 + 3] = A.w;
    }

    // ---- 16x16 projection for both windows, weights via ds_read_b128 broadcast
    float uA[16], uB[16];
#pragma unroll
    for (int o = 0; o < 16; ++o) {
        const f4* wrow = reinterpret_cast<const f4*>(&sw[o][0]);
        float a = sb[o], b = sb[o];
#pragma unroll
        for (int g = 0; g < 4; ++g) {
            f4 w = wrow[g];
#pragma unroll
            for (int k = 0; k < 4; ++k) {
                a += w[k] * v[g * 4 + k];
                b += w[k] * v[16 + g * 4 + k];
            }
        }
        uA[o] = a; uB[o] = b;
    }

    // ---- scatter: dense float4 (own pair0' + neighbor's pair1' via shfl_up)
    auto store_row = [&](int row, float u0, float u1, float u2, float u3) {
        float* rowp = op + row * WDIM;
        float sz = __shfl_up(u2, 1);   // window (Q-1) pair1'
        float sww = __shfl_up(u3, 1);
        if (firstlane) {
            *reinterpret_cast<f2*>(rowp + c0) = f2{u0, u1};
        } else {
            *reinterpret_cast<f4*>(rowp + c0) = f4{u0, u1, sz, sww};
        }
        if (lastlane) {
            *reinterpret_cast<f2*>(rowp + c2) = f2{u2, u3};
        }
    };
#pragma unroll
    for (int r = 0; r < 4; ++r)
        store_row(rows[r], uA[r * 4 + 0], uA[r * 4 + 1], uA[r * 4 + 2], uA[r * 4 + 3]);
#pragma unroll
    for (int r = 0; r < 4; ++r)
        store_row(rows[r + 4], uB[r * 4 + 0], uB[r * 4 + 1], uB[r * 4 + 2], uB[r * 4 + 3]);
}

extern "C" void kernel_launch(void* const* d_in, const int* in_sizes, int n_in,
                              void* d_out, int out_size, void* d_ws, size_t ws_size,
                              hipStream_t stream) {
    const float* x  = (const float*)d_in[0];
    const float* fw = (const float*)d_in[1];
    const float* fb = (const float*)d_in[2];
    float* out = (float*)d_out;

    // threads = B*C * 64 P-pairs * 128 Q = 2,097,152 -> 8192 blocks of 256
    const int blocks = (2 * 128 * 64 * 128) / 256;
    srm_fused_kernel<<<blocks, 256, 0, stream>>>(x, fw, fb, out);
}

// Round 3
// 102.863 us; speedup vs baseline: 2.4511x; 2.4511x over previous
//
#include <hip/hip_runtime.h>

// SRM fused kernel, M=4, S=2, B=2, C=128, H=W=512.
//
// Verified algebra (round 1 passed): per window (P,Q) the 16 gather coords
// equal the 16 scatter coords: rows {4P-2,4P-1,4P+4,4P+5}, cols
// {4Q-2,4Q-1,4Q+4,4Q+5}, clamped to {0,1}/{510,511} at edges. Rows (and
// cols) partition bijectively across windows.
//
// Block = (bc, P-pair p): owns 8 global rows
//   {8p-2,8p-1, 8p+2..8p+5, 8p+8,8p+9} (clamped at p=0 / p=63),
// stages them in a 16 KB LDS tile with aligned dense float4, computes the
// 2x128 windows (one per thread) reading/writing the tile, stores the same
// 8 rows back densely. Weights/bias are read via wave-uniform loads ->
// s_load -> SGPR operand in v_fma (no LDS weight traffic).

typedef float f4 __attribute__((ext_vector_type(4)));

__global__ __launch_bounds__(256) void srm_kernel(
    const float* __restrict__ x, const float* __restrict__ fw,
    const float* __restrict__ fb, float* __restrict__ out)
{
    __shared__ __align__(16) float tile[8 * 512];   // 16 KB, reused in+out

    const int t   = threadIdx.x;
    const int blk = blockIdx.x;
    const int p   = blk & 63;            // row-strip pair index
    const int bc  = blk >> 6;            // b*C + c in [0,256)

    const float* xp = x   + (size_t)bc * (512 * 512);
    float*       op = out + (size_t)bc * (512 * 512);

    // ---- stage in: 8 rows x 512 cols, lane-dense aligned float4
    int gaddr[4];
#pragma unroll
    for (int k = 0; k < 4; ++k) {
        const int i  = t + 256 * k;          // f4 index in [0,1024)
        const int l  = i >> 7;               // local row 0..7
        const int c4 = (i & 127) << 2;       // float col, 16B aligned
        int g;                               // global row for local row l
        if (l < 2)      g = (p == 0)  ? l         : (8 * p - 2 + l);
        else if (l < 6) g = 8 * p + l;
        else            g = (p == 63) ? (504 + l) : (8 * p + 2 + l);
        gaddr[k] = g * 512 + c4;
        *reinterpret_cast<f4*>(&tile[l * 512 + c4]) =
            *reinterpret_cast<const f4*>(xp + gaddr[k]);
    }
    __syncthreads();

    // ---- per-thread window: strip s (P = 2p+s), window Q
    const int Q  = t & 127;
    const int s  = t >> 7;
    const int c0 = (Q == 0)   ? 0   : 4 * Q - 2;
    const int c2 = (Q == 127) ? 510 : 4 * Q + 4;
    const int L0 = 2 * s;   // local rows: L0, L0+1, L0+4, L0+5

    float v[16];
#pragma unroll
    for (int j = 0; j < 4; ++j) {
        const int L = L0 + ((j < 2) ? j : j + 2);
        const float* rp = &tile[L * 512];
        v[4 * j + 0] = rp[c0];  v[4 * j + 1] = rp[c0 + 1];
        v[4 * j + 2] = rp[c2];  v[4 * j + 3] = rp[c2 + 1];
    }
    __syncthreads();   // all gathers done before tile is overwritten

    // ---- 16x16 matvec; weights via uniform (scalar) loads, chunked so the
    // register allocator keeps ~64 weight SGPRs live at a time
    float u[16];
#pragma unroll
    for (int o = 0; o < 16; ++o) u[o] = fb[o];
#pragma unroll
    for (int og = 0; og < 4; ++og) {
#pragma unroll
        for (int oo = 0; oo < 4; ++oo) {
            const int o = 4 * og + oo;
            float acc = u[o];
#pragma unroll
            for (int f = 0; f < 16; ++f) acc += fw[16 * o + f] * v[f];
            u[o] = acc;
        }
    }

    // ---- scatter results back into the tile (coords = gather coords)
#pragma unroll
    for (int j = 0; j < 4; ++j) {
        const int L = L0 + ((j < 2) ? j : j + 2);
        float* rp = &tile[L * 512];
        rp[c0] = u[4 * j + 0];  rp[c0 + 1] = u[4 * j + 1];
        rp[c2] = u[4 * j + 2];  rp[c2 + 1] = u[4 * j + 3];
    }
    __syncthreads();

    // ---- stage out: same 8 rows, lane-dense aligned float4
#pragma unroll
    for (int k = 0; k < 4; ++k) {
        const int i  = t + 256 * k;
        const int l  = i >> 7;
        const int c4 = (i & 127) << 2;
        *reinterpret_cast<f4*>(op + gaddr[k]) =
            *reinterpret_cast<const f4*>(&tile[l * 512 + c4]);
    }
}

extern "C" void kernel_launch(void* const* d_in, const int* in_sizes, int n_in,
                              void* d_out, int out_size, void* d_ws, size_t ws_size,
                              hipStream_t stream) {
    const float* x  = (const float*)d_in[0];
    const float* fw = (const float*)d_in[1];
    const float* fb = (const float*)d_in[2];
    float* out = (float*)d_out;

    // blocks = bc(256) * p(64) = 16384
    srm_kernel<<<16384, 256, 0, stream>>>(x, fw, fb, out);
}

// Round 4
// 88.369 us; speedup vs baseline: 2.8531x; 1.1640x over previous
//
#include <hip/hip_runtime.h>

// SRM fused kernel, M=4, S=2, B=2, C=128, H=W=512.
//
// Verified algebra (rounds 1/3 passed): per window (P,Q) the 16 gather
// coords equal the 16 scatter coords: rows {4P-2,4P-1,4P+4,4P+5}, cols
// {4Q-2,4Q-1,4Q+4,4Q+5}, clamped to {0,1}/{510,511} at edges; the coord
// map is a bijection (each (row,col) belongs to exactly one window).
//
// Block = (bc, p): owns 8 global rows {8p-2,8p-1, 8p+2..8p+5, 8p+8,8p+9}
// (clamped at p=0/63). Stage-in via global_load_lds width=16 (layout is
// wave-uniform base + lane*16 by construction), per-thread 16x16 matvec
// with SGPR weights, scatter back into the tile (same coords -> no barrier
// needed between gather and scatter), stage-out with NON-TEMPORAL float4
// stores so the 256 MB output stream does not evict the L3-resident input.

typedef float f4 __attribute__((ext_vector_type(4)));
typedef unsigned int u32;

__global__ __launch_bounds__(256) void srm_kernel(
    const float* __restrict__ x, const float* __restrict__ fw,
    const float* __restrict__ fb, float* __restrict__ out)
{
    __shared__ __align__(16) float tile[8 * 512];   // 16 KB

    const int t   = threadIdx.x;
    const int blk = blockIdx.x;
    const int p   = blk & 63;            // row-strip index
    const int bc  = blk >> 6;            // b*C + c in [0,256)

    const float* xp = x   + (size_t)bc * (512 * 512);
    float*       op = out + (size_t)bc * (512 * 512);

    const int tl = t >> 7;               // 0 or 1
    const int c4 = (t & 127) << 2;       // float col of this thread's f4 chunk

    // global rows for local rows l = tl + 2k, k = 0..3
    int gaddr[4];
    {
        int l, g;
        l = tl;     g = (p == 0)  ? l         : (8 * p - 2 + l);  gaddr[0] = g * 512 + c4;
        l = tl + 2; g = 8 * p + l;                                gaddr[1] = g * 512 + c4;
        l = tl + 4; g = 8 * p + l;                                gaddr[2] = g * 512 + c4;
        l = tl + 6; g = (p == 63) ? (504 + l) : (8 * p + 2 + l);  gaddr[3] = g * 512 + c4;
    }

    // ---- stage in: direct global->LDS, 16 B per lane, lane-dense
#pragma unroll
    for (int k = 0; k < 4; ++k) {
        const int l = tl + 2 * k;
        __builtin_amdgcn_global_load_lds(
            (const __attribute__((address_space(1))) u32*)(const void*)(xp + gaddr[k]),
            (__attribute__((address_space(3))) u32*)(void*)&tile[l * 512 + c4],
            16, 0, 0);
    }
    __syncthreads();

    // ---- per-thread window: strip s (row pair), window Q
    const int Q  = t & 127;
    const int s  = t >> 7;
    const int c0 = (Q == 0)   ? 0   : 4 * Q - 2;
    const int c2 = (Q == 127) ? 510 : 4 * Q + 4;
    const int L0 = 2 * s;   // local rows: L0, L0+1, L0+4, L0+5

    float v[16];
#pragma unroll
    for (int j = 0; j < 4; ++j) {
        const int L = L0 + ((j < 2) ? j : j + 2);
        const float* rp = &tile[L * 512];
        v[4 * j + 0] = rp[c0];  v[4 * j + 1] = rp[c0 + 1];
        v[4 * j + 2] = rp[c2];  v[4 * j + 3] = rp[c2 + 1];
    }

    // ---- 16x16 matvec; weights/bias via wave-uniform (scalar) loads
    float u[16];
#pragma unroll
    for (int o = 0; o < 16; ++o) u[o] = fb[o];
#pragma unroll
    for (int o = 0; o < 16; ++o) {
        float acc = u[o];
#pragma unroll
        for (int f = 0; f < 16; ++f) acc += fw[16 * o + f] * v[f];
        u[o] = acc;
    }

    // ---- scatter back into tile: same coords this thread gathered,
    // so no barrier is needed between gather and scatter
#pragma unroll
    for (int j = 0; j < 4; ++j) {
        const int L = L0 + ((j < 2) ? j : j + 2);
        float* rp = &tile[L * 512];
        rp[c0] = u[4 * j + 0];  rp[c0 + 1] = u[4 * j + 1];
        rp[c2] = u[4 * j + 2];  rp[c2 + 1] = u[4 * j + 3];
    }
    __syncthreads();

    // ---- stage out: same 8 rows, lane-dense f4, NON-TEMPORAL so the
    // output stream doesn't evict the input from L2/L3
#pragma unroll
    for (int k = 0; k < 4; ++k) {
        const int l = tl + 2 * k;
        f4 val = *reinterpret_cast<const f4*>(&tile[l * 512 + c4]);
        __builtin_nontemporal_store(val, reinterpret_cast<f4*>(op + gaddr[k]));
    }
}

extern "C" void kernel_launch(void* const* d_in, const int* in_sizes, int n_in,
                              void* d_out, int out_size, void* d_ws, size_t ws_size,
                              hipStream_t stream) {
    const float* x  = (const float*)d_in[0];
    const float* fw = (const float*)d_in[1];
    const float* fb = (const float*)d_in[2];
    float* out = (float*)d_out;

    // blocks = bc(256) * p(64) = 16384
    srm_kernel<<<16384, 256, 0, stream>>>(x, fw, fb, out);
}

// Round 5
// 87.538 us; speedup vs baseline: 2.8802x; 1.0095x over previous
//
#include <hip/hip_runtime.h>

// SRM fused kernel, M=4, S=2, B=2, C=128, H=W=512.
//
// Verified algebra (rounds 1/3/4 passed): per window (P,Q) the 16 gather
// coords equal the 16 scatter coords: rows {4P-2,4P-1,4P+4,4P+5}, cols
// {4Q-2,4Q-1,4Q+4,4Q+5}, clamped at edges; the coord map is a bijection.
//
// Block = (bc, p): owns 8 global rows {8p-2,8p-1, 8p+2..8p+5, 8p+8,8p+9}
// (clamped at p=0/63). Stage-in via global_load_lds width=16 with
// PRE-SWIZZLED global source columns (LDS dest stays linear, per rule:
// swizzle both sides or neither); gather/scatter use the same XOR
// involution so the stride-16B access pattern drops from 8-way to 2-way
// bank conflicts. Stage-out reads LDS at the swizzled chunk, stores
// linear/coalesced non-temporal float4.
//
// Swizzle (involution): 8B units  sigma(u) = u ^ (((u>>5)&3)<<2)
//                       16B chunks  tau(c) = c ^ (((c>>4)&3)<<1)
// tau permutes within aligned 128B groups -> global coalescing unchanged.

typedef float f4 __attribute__((ext_vector_type(4)));
typedef float f2 __attribute__((ext_vector_type(2)));
typedef unsigned int u32;

__device__ __forceinline__ int swz_u(int u) { return u ^ (((u >> 5) & 3) << 2); }
__device__ __forceinline__ int swz_c(int c) { return c ^ (((c >> 4) & 3) << 1); }

__global__ __launch_bounds__(256) void srm_kernel(
    const float* __restrict__ x, const float* __restrict__ fw,
    const float* __restrict__ fb, float* __restrict__ out)
{
    __shared__ __align__(16) float tile[8 * 512];   // 16 KB

    const int t   = threadIdx.x;
    const int blk = blockIdx.x;
    const int p   = blk & 63;            // row-strip index
    const int bc  = blk >> 6;            // b*C + c in [0,256)

    const float* xp = x   + (size_t)bc * (512 * 512);
    float*       op = out + (size_t)bc * (512 * 512);

    const int tl    = t >> 7;            // 0 or 1
    const int clin  = t & 127;           // linear 16B chunk index within row
    const int cswz4 = swz_c(clin) << 2;  // swizzled chunk -> float col

    // global rows for local rows l = tl + 2k, k = 0..3
    int grow[4];
    {
        int l;
        l = tl;     grow[0] = (p == 0)  ? l         : (8 * p - 2 + l);
        l = tl + 2; grow[1] = 8 * p + l;
        l = tl + 4; grow[2] = 8 * p + l;
        l = tl + 6; grow[3] = (p == 63) ? (504 + l) : (8 * p + 2 + l);
    }

    // ---- stage in: direct global->LDS; LDS dest linear (lane*16), global
    // source column pre-swizzled so LDS unit sigma(u) holds global unit u
#pragma unroll
    for (int k = 0; k < 4; ++k) {
        const int l = tl + 2 * k;
        __builtin_amdgcn_global_load_lds(
            (const __attribute__((address_space(1))) u32*)(const void*)
                (xp + grow[k] * 512 + cswz4),
            (__attribute__((address_space(3))) u32*)(void*)
                (&tile[l * 512] + clin * 4),
            16, 0, 0);
    }
    __syncthreads();

    // ---- per-thread window: strip s (row pair), window Q
    const int Q  = t & 127;
    const int s  = t >> 7;
    const int c0 = (Q == 0)   ? 0   : 4 * Q - 2;   // always even
    const int c2 = (Q == 127) ? 510 : 4 * Q + 4;   // always even
    const int L0 = 2 * s;   // local rows: L0, L0+1, L0+4, L0+5
    const int a0 = swz_u(c0 >> 1) << 1;   // swizzled float index of pair0
    const int a1 = swz_u(c2 >> 1) << 1;   // swizzled float index of pair1

    float v[16];
#pragma unroll
    for (int j = 0; j < 4; ++j) {
        const int L = L0 + ((j < 2) ? j : j + 2);
        const float* rp = &tile[L * 512];
        f2 e0 = *reinterpret_cast<const f2*>(rp + a0);
        f2 e1 = *reinterpret_cast<const f2*>(rp + a1);
        v[4 * j + 0] = e0.x;  v[4 * j + 1] = e0.y;
        v[4 * j + 2] = e1.x;  v[4 * j + 3] = e1.y;
    }

    // ---- 16x16 matvec; weights/bias via wave-uniform (scalar) loads
    float u[16];
#pragma unroll
    for (int o = 0; o < 16; ++o) u[o] = fb[o];
#pragma unroll
    for (int o = 0; o < 16; ++o) {
        float acc = u[o];
#pragma unroll
        for (int f = 0; f < 16; ++f) acc += fw[16 * o + f] * v[f];
        u[o] = acc;
    }

    // ---- scatter back into tile: same (swizzled) coords this thread
    // gathered -> no barrier needed between gather and scatter
#pragma unroll
    for (int j = 0; j < 4; ++j) {
        const int L = L0 + ((j < 2) ? j : j + 2);
        float* rp = &tile[L * 512];
        *reinterpret_cast<f2*>(rp + a0) = f2{u[4 * j + 0], u[4 * j + 1]};
        *reinterpret_cast<f2*>(rp + a1) = f2{u[4 * j + 2], u[4 * j + 3]};
    }
    __syncthreads();

    // ---- stage out: read LDS at swizzled chunk, store linear coalesced
    // NON-TEMPORAL float4 so the output stream doesn't evict the input
#pragma unroll
    for (int k = 0; k < 4; ++k) {
        const int l = tl + 2 * k;
        f4 val = *reinterpret_cast<const f4*>(&tile[l * 512 + cswz4]);
        __builtin_nontemporal_store(
            val, reinterpret_cast<f4*>(op + grow[k] * 512 + clin * 4));
    }
}

extern "C" void kernel_launch(void* const* d_in, const int* in_sizes, int n_in,
                              void* d_out, int out_size, void* d_ws, size_t ws_size,
                              hipStream_t stream) {
    const float* x  = (const float*)d_in[0];
    const float* fw = (const float*)d_in[1];
    const float* fb = (const float*)d_in[2];
    float* out = (float*)d_out;

    // blocks = bc(256) * p(64) = 16384
    srm_kernel<<<16384, 256, 0, stream>>>(x, fw, fb, out);
}

// Round 6
// 86.431 us; speedup vs baseline: 2.9171x; 1.0128x over previous
//
#include <hip/hip_runtime.h>

// SRM fused kernel, M=4, S=2, B=2, C=128, H=W=512.
//
// Verified algebra (rounds 1/3/4/5 passed): per window (P,Q) the 16 gather
// coords equal the 16 scatter coords: rows {4P-2,4P-1,4P+4,4P+5}, cols
// {4Q-2,4Q-1,4Q+4,4Q+5}, clamped at edges; the coord map is a bijection.
// Column structure per row: window Q touches floats {4Q-2,4Q-1} (hi-half of
// 16B chunk Q-1) and {4Q+4,4Q+5} (lo-half of chunk Q+1).
//
// This version: NO strided LDS access anywhere. Each lane reads/writes only
// its OWN chunk (lane-linear ds_read_b128/ds_write_b128 -> conflict-free;
// lanes tile all 32 banks exactly), neighbor halves move via __shfl_up/down.
// Wave-edge lanes (c=0/63/64/127) patch via clamp identities or tiny aligned
// b64 LDS ops; all cross-wave locations are produced and consumed by the
// SAME thread, so no middle barrier and no races:
//   - chunk64 lo = window63 pair1' (wave-A lane63 writes it, and is also its
//     only gather reader); chunk63 hi = window64 pair0' (wave-B lane0 both).
//   - the racy halves of the neighboring b128 gathers are dead values.

typedef float f4 __attribute__((ext_vector_type(4)));
typedef float f2 __attribute__((ext_vector_type(2)));
typedef unsigned int u32;

__global__ __launch_bounds__(256) void srm_kernel(
    const float* __restrict__ x, const float* __restrict__ fw,
    const float* __restrict__ fb, float* __restrict__ out)
{
    __shared__ __align__(16) float tile[8 * 512];   // 16 KB

    const int t   = threadIdx.x;
    const int blk = blockIdx.x;
    const int p   = blk & 63;            // row-strip index
    const int bc  = blk >> 6;            // b*C + c in [0,256)

    const float* xp = x   + (size_t)bc * (512 * 512);
    float*       op = out + (size_t)bc * (512 * 512);

    const int tl   = t >> 7;             // 0 or 1
    const int clin = t & 127;            // 16B chunk index within row

    // global rows for local rows l = tl + 2k, k = 0..3
    int grow[4];
    {
        int l;
        l = tl;     grow[0] = (p == 0)  ? l         : (8 * p - 2 + l);
        l = tl + 2; grow[1] = 8 * p + l;
        l = tl + 4; grow[2] = 8 * p + l;
        l = tl + 6; grow[3] = (p == 63) ? (504 + l) : (8 * p + 2 + l);
    }

    // ---- stage in: direct global->LDS, linear both sides, 16 B per lane
#pragma unroll
    for (int k = 0; k < 4; ++k) {
        const int l = tl + 2 * k;
        __builtin_amdgcn_global_load_lds(
            (const __attribute__((address_space(1))) u32*)(const void*)
                (xp + grow[k] * 512 + clin * 4),
            (__attribute__((address_space(3))) u32*)(void*)
                (&tile[l * 512] + clin * 4),
            16, 0, 0);
    }
    __syncthreads();

    // ---- per-thread window: strip s, window/chunk c = clin
    const int c    = clin;
    const int s    = tl;
    const int L0   = 2 * s;              // window rows: L0, L0+1, L0+4, L0+5
    const int lane = t & 63;

    // gather: own-chunk b128 + neighbor halves via shuffles
    float v[16];
#pragma unroll
    for (int j = 0; j < 4; ++j) {
        const int L = L0 + ((j < 2) ? j : j + 2);
        const float* rp = &tile[L * 512];
        f4 A = *reinterpret_cast<const f4*>(rp + 4 * c);
        // pair0 = {4c-2,4c-1} = hi-half of chunk c-1
        float p0x = __shfl_up(A.z, 1);
        float p0y = __shfl_up(A.w, 1);
        // pair1 = {4c+4,4c+5} = lo-half of chunk c+1
        float p1x = __shfl_down(A.x, 1);
        float p1y = __shfl_down(A.y, 1);
        if (lane == 0) {
            if (c == 0) { p0x = A.x; p0y = A.y; }          // clamp: pair0={0,1}
            else {                                         // c==64
                f2 e = *reinterpret_cast<const f2*>(rp + 4 * c - 2);
                p0x = e.x; p0y = e.y;
            }
        }
        if (lane == 63) {
            if (c == 127) { p1x = A.z; p1y = A.w; }        // clamp: pair1={510,511}
            else {                                         // c==63
                f2 e = *reinterpret_cast<const f2*>(rp + 4 * c + 4);
                p1x = e.x; p1y = e.y;
            }
        }
        v[4 * j + 0] = p0x;  v[4 * j + 1] = p0y;
        v[4 * j + 2] = p1x;  v[4 * j + 3] = p1y;
    }

    // ---- 16x16 matvec; weights/bias via wave-uniform (scalar) loads
    float u[16];
#pragma unroll
    for (int o = 0; o < 16; ++o) u[o] = fb[o];
#pragma unroll
    for (int o = 0; o < 16; ++o) {
        float acc = u[o];
#pragma unroll
        for (int f = 0; f < 16; ++f) acc += fw[16 * o + f] * v[f];
        u[o] = acc;
    }

    // ---- scatter: assemble own chunk via shuffles, conflict-free b128 write
    // chunk c = [window(c-1) pair1' | window(c+1) pair0']
#pragma unroll
    for (int j = 0; j < 4; ++j) {
        const int L = L0 + ((j < 2) ? j : j + 2);
        float* rp = &tile[L * 512];
        float lox = __shfl_up(u[4 * j + 2], 1);
        float loy = __shfl_up(u[4 * j + 3], 1);
        float hix = __shfl_down(u[4 * j + 0], 1);
        float hiy = __shfl_down(u[4 * j + 1], 1);
        bool fullw = true;
        if (lane == 0) {
            if (c == 0) { lox = u[4 * j + 0]; loy = u[4 * j + 1]; }  // clamp
            else {  // c==64: own pair0' -> chunk63 hi; write only own hi-half
                *reinterpret_cast<f2*>(rp + 254) = f2{u[4 * j + 0], u[4 * j + 1]};
                *reinterpret_cast<f2*>(rp + 4 * c + 2) = f2{hix, hiy};
                fullw = false;
            }
        }
        if (lane == 63) {
            if (c == 127) { hix = u[4 * j + 2]; hiy = u[4 * j + 3]; }  // clamp
            else {  // c==63: own pair1' -> chunk64 lo; write only own lo-half
                *reinterpret_cast<f2*>(rp + 256) = f2{u[4 * j + 2], u[4 * j + 3]};
                *reinterpret_cast<f2*>(rp + 4 * c) = f2{lox, loy};
                fullw = false;
            }
        }
        if (fullw)
            *reinterpret_cast<f4*>(rp + 4 * c) = f4{lox, loy, hix, hiy};
    }
    __syncthreads();

    // ---- stage out: linear conflict-free b128 reads, coalesced NT stores
#pragma unroll
    for (int k = 0; k < 4; ++k) {
        const int l = tl + 2 * k;
        f4 val = *reinterpret_cast<const f4*>(&tile[l * 512 + clin * 4]);
        __builtin_nontemporal_store(
            val, reinterpret_cast<f4*>(op + grow[k] * 512 + clin * 4));
    }
}

extern "C" void kernel_launch(void* const* d_in, const int* in_sizes, int n_in,
                              void* d_out, int out_size, void* d_ws, size_t ws_size,
                              hipStream_t stream) {
    const float* x  = (const float*)d_in[0];
    const float* fw = (const float*)d_in[1];
    const float* fb = (const float*)d_in[2];
    float* out = (float*)d_out;

    // blocks = bc(256) * p(64) = 16384
    srm_kernel<<<16384, 256, 0, stream>>>(x, fw, fb, out);
}